// Round 1
// baseline (1041.557 us; speedup 1.0000x reference)
//
#include <hip/hip_runtime.h>

#define EPS 1e-5f

constexpr int Bn = 16384;   // batch
constexpr int Fd = 256;     // features
constexpr int Md = 64;      // magnitude bins
constexpr int Dd = 4096;    // directions
constexpr int NBINS = 1024; // counts values are in [0,1000)

// ---------------------------------------------------------------------------
// Kernel 1: value-weighted histogram of counts.
// W[t] = t * (#entries == t)  ->  prefix-sum gives sum of entries <= c.
// ---------------------------------------------------------------------------
__global__ void hist_kernel(const int* __restrict__ counts, unsigned* __restrict__ W, int n) {
    __shared__ unsigned lh[NBINS];
    for (int i = threadIdx.x; i < NBINS; i += blockDim.x) lh[i] = 0u;
    __syncthreads();
    for (int i = blockIdx.x * blockDim.x + threadIdx.x; i < n; i += gridDim.x * blockDim.x) {
        int c = counts[i];
        c = min(max(c, 0), NBINS - 1);
        if (c > 0) atomicAdd(&lh[c], (unsigned)c);
    }
    __syncthreads();
    for (int i = threadIdx.x; i < NBINS; i += blockDim.x)
        if (lh[i]) atomicAdd(&W[i], lh[i]);
}

// ---------------------------------------------------------------------------
// Kernel 2: inclusive prefix scan of W (1024 bins, single block).
// cum[c] = sum of all count entries with value <= c; cum[1023] = total sum.
// ---------------------------------------------------------------------------
__global__ void scan_kernel(const unsigned* __restrict__ W, unsigned* __restrict__ cum) {
    __shared__ unsigned s[NBINS];
    int t = threadIdx.x;
    s[t] = W[t];
    __syncthreads();
    for (int off = 1; off < NBINS; off <<= 1) {
        unsigned v = (t >= off) ? s[t - off] : 0u;
        __syncthreads();
        s[t] += v;
        __syncthreads();
    }
    cum[t] = s[t];
}

// ---------------------------------------------------------------------------
// Kernel 3: row norms of normalized vectors + magnitude bin (searchsorted right).
// One wave (64 lanes) per row; lane loads 4 floats (F=256).
// ---------------------------------------------------------------------------
__global__ void norm_mi_kernel(const float4* __restrict__ vec4,
                               const float4* __restrict__ mean4,
                               const float4* __restrict__ std4,
                               const float* __restrict__ mags,
                               int* __restrict__ mi, int nrows) {
    int wave = threadIdx.x >> 6;
    int lane = threadIdx.x & 63;
    int row = blockIdx.x * 4 + wave;
    if (row >= nrows) return;
    float4 x = vec4[row * (Fd / 4) + lane];
    float4 m = mean4[lane];
    float4 s = std4[lane];
    float v0 = (x.x - m.x) / (s.x + EPS);
    float v1 = (x.y - m.y) / (s.y + EPS);
    float v2 = (x.z - m.z) / (s.z + EPS);
    float v3 = (x.w - m.w) / (s.w + EPS);
    float ss = v0 * v0 + v1 * v1 + v2 * v2 + v3 * v3;
    #pragma unroll
    for (int o = 32; o; o >>= 1) ss += __shfl_down(ss, o, 64);
    if (lane == 0) {
        float nrm = sqrtf(ss);
        int cnt = 0;
        #pragma unroll
        for (int i = 0; i < Md; ++i) cnt += (mags[i] <= nrm) ? 1 : 0;
        mi[row] = min(cnt, Md - 1);
    }
}

// ---------------------------------------------------------------------------
// Kernel 4: fused GEMM-argmax + output write.
// Block: 256 threads, BM=32 rows x all D=4096 dirs (tiles of BN=128).
// A (normalized on the fly) held full-K in LDS; B chunked KC=64.
// Padding: As stride 260 floats, Bs stride 68 floats -> <=2-way bank aliasing
// on float4 reads (free on CDNA4).
// ---------------------------------------------------------------------------
#define BM 32
#define BN 128
#define KC 64
#define AS_LD 260
#define BS_LD 68

__global__ __launch_bounds__(256, 2) void gemm_argmax_kernel(
        const float* __restrict__ vecs, const float* __restrict__ mean,
        const float* __restrict__ stdv, const float* __restrict__ dirs,
        const int* __restrict__ counts, const int* __restrict__ mi,
        const unsigned* __restrict__ cum, float* __restrict__ out, int nrows) {
    __shared__ float As[BM * AS_LD];   // 33280 B
    __shared__ float Bs[BN * BS_LD];   // 34816 B
    int tid = threadIdx.x;
    int tx = tid & 15, ty = tid >> 4;
    int row0 = blockIdx.x * BM;

    // Load A (32 rows x 256 K) with normalization. 512 float4s, 2 per thread... 8 iters of 256.
    #pragma unroll
    for (int it = 0; it < 8; ++it) {
        int idx = it * 256 + tid;
        int r = idx >> 6, kv = idx & 63;
        float4 x = *(const float4*)&vecs[(row0 + r) * Fd + kv * 4];
        float4 m = *(const float4*)&mean[kv * 4];
        float4 s = *(const float4*)&stdv[kv * 4];
        float4 v;
        v.x = (x.x - m.x) / (s.x + EPS);
        v.y = (x.y - m.y) / (s.y + EPS);
        v.z = (x.z - m.z) / (s.z + EPS);
        v.w = (x.w - m.w) / (s.w + EPS);
        *(float4*)&As[r * AS_LD + kv * 4] = v;
    }

    float best0 = -INFINITY, best1 = -INFINITY;
    int bidx0 = 0, bidx1 = 0;

    for (int ct = 0; ct < Dd / BN; ++ct) {
        float acc[2][8];
        #pragma unroll
        for (int j = 0; j < 8; ++j) { acc[0][j] = 0.f; acc[1][j] = 0.f; }

        for (int kc = 0; kc < Fd / KC; ++kc) {
            __syncthreads();  // previous compute (or A-load) done before Bs overwrite
            #pragma unroll
            for (int it = 0; it < 8; ++it) {
                int idx = it * 256 + tid;
                int r = idx >> 4, kv = idx & 15;
                float4 b = *(const float4*)&dirs[(ct * BN + r) * Fd + kc * KC + kv * 4];
                *(float4*)&Bs[r * BS_LD + kv * 4] = b;
            }
            __syncthreads();
            int kbase = kc * KC;
            #pragma unroll
            for (int ks = 0; ks < KC; ks += 4) {
                float4 a0 = *(const float4*)&As[ty * AS_LD + kbase + ks];
                float4 a1 = *(const float4*)&As[(ty + 16) * AS_LD + kbase + ks];
                #pragma unroll
                for (int j = 0; j < 8; ++j) {
                    float4 b = *(const float4*)&Bs[(tx + 16 * j) * BS_LD + ks];
                    acc[0][j] += a0.x * b.x + a0.y * b.y + a0.z * b.z + a0.w * b.w;
                    acc[1][j] += a1.x * b.x + a1.y * b.y + a1.z * b.z + a1.w * b.w;
                }
            }
        }
        // running argmax; per-thread gc sequence is ascending -> strict > keeps first max
        #pragma unroll
        for (int j = 0; j < 8; ++j) {
            int gc = ct * BN + tx + 16 * j;
            if (acc[0][j] > best0) { best0 = acc[0][j]; bidx0 = gc; }
            if (acc[1][j] > best1) { best1 = acc[1][j]; bidx1 = gc; }
        }
    }

    // cross-thread argmax reduce (16 threads share each row), reusing As
    __syncthreads();
    float* redv = As;
    int* redi = (int*)&As[BM * 16];
    redv[ty * 16 + tx] = best0;        redi[ty * 16 + tx] = bidx0;
    redv[(ty + 16) * 16 + tx] = best1; redi[(ty + 16) * 16 + tx] = bidx1;
    __syncthreads();
    if (tid < BM) {
        float bv = redv[tid * 16];
        int bi = redi[tid * 16];
        #pragma unroll
        for (int t = 1; t < 16; ++t) {
            float v = redv[tid * 16 + t];
            int ii = redi[tid * 16 + t];
            if (v > bv || (v == bv && ii < bi)) { bv = v; bi = ii; }
        }
        int gr = row0 + tid;
        if (gr < nrows) {
            int mival = mi[gr];
            int c = counts[mival * Dd + bi];
            unsigned totU = cum[NBINS - 1];
            if (totU == 0u) totU = 1u;
            float tf = (float)totU;
            int cc = min(max(c, 0), NBINS - 1);
            float cl = (float)cum[cc];
            out[gr] = (float)c;
            out[nrows + gr] = (float)c / tf;
            out[2 * nrows + gr] = (cl - 0.5f * (float)c) / tf;
        }
    }
}

// ---------------------------------------------------------------------------
extern "C" void kernel_launch(void* const* d_in, const int* in_sizes, int n_in,
                              void* d_out, int out_size, void* d_ws, size_t ws_size,
                              hipStream_t stream) {
    const float* vecs = (const float*)d_in[0];
    const float* mean = (const float*)d_in[1];
    const float* stdv = (const float*)d_in[2];
    const float* mags = (const float*)d_in[3];
    const float* dirs = (const float*)d_in[4];
    const int* counts = (const int*)d_in[5];
    float* out = (float*)d_out;

    unsigned* W = (unsigned*)d_ws;
    unsigned* cum = W + NBINS;
    int* mi = (int*)(cum + NBINS);

    int nC = in_sizes[5];  // M*D = 262144

    hipMemsetAsync(d_ws, 0, NBINS * sizeof(unsigned), stream);

    hist_kernel<<<256, 256, 0, stream>>>(counts, W, nC);
    scan_kernel<<<1, NBINS, 0, stream>>>(W, cum);
    norm_mi_kernel<<<Bn / 4, 256, 0, stream>>>(
        (const float4*)vecs, (const float4*)mean, (const float4*)stdv, mags, mi, Bn);
    gemm_argmax_kernel<<<Bn / BM, 256, 0, stream>>>(
        vecs, mean, stdv, dirs, counts, mi, cum, out, Bn);
}

// Round 2
// 333.768 us; speedup vs baseline: 3.1206x; 3.1206x over previous
//
#include <hip/hip_runtime.h>

#define EPS 1e-5f

constexpr int Bn = 16384;   // batch
constexpr int Fd = 256;     // features
constexpr int Md = 64;      // magnitude bins
constexpr int Dd = 4096;    // directions
constexpr int NBINS = 1024; // counts values are in [0,1000)
constexpr float TAU = 2e-3f; // rescue threshold (>> 2e-5 split error bound)

typedef _Float16 half8 __attribute__((ext_vector_type(8)));
typedef _Float16 half4v __attribute__((ext_vector_type(4)));
typedef float f32x4 __attribute__((ext_vector_type(4)));

// workspace layout (bytes)
constexpr size_t WS_W   = 0;                      // u32[1024]
constexpr size_t WS_CUM = 4096;                   // u32[1024]
constexpr size_t WS_MI  = 8192;                   // int[16384]
constexpr size_t WS_T2V = 73728;                  // float2[16384]
constexpr size_t WS_T2I = 204800;                 // int2[16384]
constexpr size_t WS_DH  = 335872;                 // f16[4096*256]
constexpr size_t WS_DL  = 2433024;                // f16[4096*256]
constexpr size_t WS_NEEDED = 4530176;

__device__ inline void split_f16(float x, _Float16& h, _Float16& l) {
    h = (_Float16)x;
    l = (_Float16)(x - (float)h);
}

// ---------------------------------------------------------------------------
// Kernel 1: value-weighted histogram of counts. W[t] = t * (#entries == t).
// ---------------------------------------------------------------------------
__global__ void hist_kernel(const int* __restrict__ counts, unsigned* __restrict__ W, int n) {
    __shared__ unsigned lh[NBINS];
    for (int i = threadIdx.x; i < NBINS; i += blockDim.x) lh[i] = 0u;
    __syncthreads();
    for (int i = blockIdx.x * blockDim.x + threadIdx.x; i < n; i += gridDim.x * blockDim.x) {
        int c = counts[i];
        c = min(max(c, 0), NBINS - 1);
        if (c > 0) atomicAdd(&lh[c], (unsigned)c);
    }
    __syncthreads();
    for (int i = threadIdx.x; i < NBINS; i += blockDim.x)
        if (lh[i]) atomicAdd(&W[i], lh[i]);
}

// ---------------------------------------------------------------------------
// Kernel 2: inclusive prefix scan of W (1024 bins, single block).
// ---------------------------------------------------------------------------
__global__ void scan_kernel(const unsigned* __restrict__ W, unsigned* __restrict__ cum) {
    __shared__ unsigned s[NBINS];
    int t = threadIdx.x;
    s[t] = W[t];
    __syncthreads();
    for (int off = 1; off < NBINS; off <<= 1) {
        unsigned v = (t >= off) ? s[t - off] : 0u;
        __syncthreads();
        s[t] += v;
        __syncthreads();
    }
    cum[t] = s[t];
}

// ---------------------------------------------------------------------------
// Kernel 3: row norms + magnitude bin (searchsorted right). One wave per row.
// ---------------------------------------------------------------------------
__global__ void norm_mi_kernel(const float4* __restrict__ vec4,
                               const float4* __restrict__ mean4,
                               const float4* __restrict__ std4,
                               const float* __restrict__ mags,
                               int* __restrict__ mi, int nrows) {
    int wave = threadIdx.x >> 6;
    int lane = threadIdx.x & 63;
    int row = blockIdx.x * 4 + wave;
    if (row >= nrows) return;
    float4 x = vec4[row * (Fd / 4) + lane];
    float4 m = mean4[lane];
    float4 s = std4[lane];
    float v0 = (x.x - m.x) / (s.x + EPS);
    float v1 = (x.y - m.y) / (s.y + EPS);
    float v2 = (x.z - m.z) / (s.z + EPS);
    float v3 = (x.w - m.w) / (s.w + EPS);
    float ss = v0 * v0 + v1 * v1 + v2 * v2 + v3 * v3;
    #pragma unroll
    for (int o = 32; o; o >>= 1) ss += __shfl_down(ss, o, 64);
    if (lane == 0) {
        float nrm = sqrtf(ss);
        int cnt = 0;
        #pragma unroll
        for (int i = 0; i < Md; ++i) cnt += (mags[i] <= nrm) ? 1 : 0;
        mi[row] = min(cnt, Md - 1);
    }
}

// ---------------------------------------------------------------------------
// Kernel 4: split dirs fp32 -> f16 hi/lo arrays (layout [d][k], k-contiguous).
// ---------------------------------------------------------------------------
__global__ void split_dirs_kernel(const float4* __restrict__ d4,
                                  half4v* __restrict__ dh4, half4v* __restrict__ dl4, int n4) {
    int i = blockIdx.x * blockDim.x + threadIdx.x;
    if (i >= n4) return;
    float4 x = d4[i];
    _Float16 h0, h1, h2, h3, l0, l1, l2, l3;
    split_f16(x.x, h0, l0); split_f16(x.y, h1, l1);
    split_f16(x.z, h2, l2); split_f16(x.w, h3, l3);
    dh4[i] = (half4v){h0, h1, h2, h3};
    dl4[i] = (half4v){l0, l1, l2, l3};
}

// ---------------------------------------------------------------------------
// Kernel 5: MFMA f16-split GEMM with per-row top-2 tracking.
// Block = 256 threads (4 waves), BM=32 rows. Wave w owns dirs [w*1024,(w+1)*1024).
// A (normalized, split) in LDS [32][264] per split; B frags direct from L2.
// Per lane: 8 row-states (2 rowtiles x 4 regs), running top-2 each.
// mfma_f32_16x16x32_f16: A lane row=l&15 k=(l>>4)*8+j ; B lane col=l&15 same k;
// C/D: col=lane&15, row=(lane>>4)*4+reg.
// ---------------------------------------------------------------------------
#define A_LD 264  // f16 elements per row (256 + 8 pad -> 2-way bank alias, free)

__global__ __launch_bounds__(256, 2) void mfma_top2_kernel(
        const float* __restrict__ vecs, const float* __restrict__ mean,
        const float* __restrict__ stdv,
        const _Float16* __restrict__ dh, const _Float16* __restrict__ dl,
        float2* __restrict__ t2v, int2* __restrict__ t2i) {
    __shared__ __align__(16) char smem[33792];
    _Float16* Ah = (_Float16*)smem;              // [32][264]
    _Float16* Al = (_Float16*)(smem + 16896);    // [32][264]

    const int tid = threadIdx.x;
    const int w = tid >> 6, lane = tid & 63;
    const int laneN = lane & 15, laneK = lane >> 4;
    const int row0 = blockIdx.x * 32;

    // ---- stage A: load 32x256 fp32, normalize, split to f16 hi/lo in LDS
    #pragma unroll
    for (int it = 0; it < 8; ++it) {
        int idx = it * 256 + tid;
        int r = idx >> 6, kv = (idx & 63) * 4;
        float4 x = *(const float4*)&vecs[(size_t)(row0 + r) * Fd + kv];
        float4 m = *(const float4*)&mean[kv];
        float4 s = *(const float4*)&stdv[kv];
        float v0 = (x.x - m.x) / (s.x + EPS);
        float v1 = (x.y - m.y) / (s.y + EPS);
        float v2 = (x.z - m.z) / (s.z + EPS);
        float v3 = (x.w - m.w) / (s.w + EPS);
        _Float16 h0, h1, h2, h3, l0, l1, l2, l3;
        split_f16(v0, h0, l0); split_f16(v1, h1, l1);
        split_f16(v2, h2, l2); split_f16(v3, h3, l3);
        *(half4v*)&Ah[r * A_LD + kv] = (half4v){h0, h1, h2, h3};
        *(half4v*)&Al[r * A_LD + kv] = (half4v){l0, l1, l2, l3};
    }
    __syncthreads();

    // ---- per-lane top-2 state for 8 rows
    float B1[8], B2[8];
    int I1[8], I2[8];
    #pragma unroll
    for (int r = 0; r < 8; ++r) { B1[r] = -3.0e38f; B2[r] = -3.0e38f; I1[r] = 0x7fffffff; I2[r] = 0x7fffffff; }

    const _Float16* A0h = &Ah[laneN * A_LD + laneK * 8];
    const _Float16* A0l = &Al[laneN * A_LD + laneK * 8];
    const _Float16* A1h = &Ah[(16 + laneN) * A_LD + laneK * 8];
    const _Float16* A1l = &Al[(16 + laneN) * A_LD + laneK * 8];
    const int dbase0 = w * 1024;
    const _Float16* Bh0 = dh + (size_t)(dbase0 + laneN) * Fd + laneK * 8;
    const _Float16* Bl0 = dl + (size_t)(dbase0 + laneN) * Fd + laneK * 8;

    const f32x4 zero = {0.f, 0.f, 0.f, 0.f};

    for (int nq = 0; nq < 16; ++nq) {       // 16 quads of 4 N-tiles = 1024 dirs
        const _Float16* BhQ = Bh0 + (size_t)nq * 64 * Fd;
        const _Float16* BlQ = Bl0 + (size_t)nq * 64 * Fd;
        f32x4 acc[2][4];
        #pragma unroll
        for (int t = 0; t < 2; ++t)
            #pragma unroll
            for (int n = 0; n < 4; ++n) acc[t][n] = zero;

        #pragma unroll
        for (int ks = 0; ks < 8; ++ks) {
            half8 a0h = *(const half8*)(A0h + ks * 32);
            half8 a0l = *(const half8*)(A0l + ks * 32);
            half8 a1h = *(const half8*)(A1h + ks * 32);
            half8 a1l = *(const half8*)(A1l + ks * 32);
            #pragma unroll
            for (int n = 0; n < 4; ++n) {
                half8 bh = *(const half8*)(BhQ + n * 16 * Fd + ks * 32);
                half8 bl = *(const half8*)(BlQ + n * 16 * Fd + ks * 32);
                acc[0][n] = __builtin_amdgcn_mfma_f32_16x16x32_f16(a0h, bh, acc[0][n], 0, 0, 0);
                acc[0][n] = __builtin_amdgcn_mfma_f32_16x16x32_f16(a0l, bh, acc[0][n], 0, 0, 0);
                acc[0][n] = __builtin_amdgcn_mfma_f32_16x16x32_f16(a0h, bl, acc[0][n], 0, 0, 0);
                acc[1][n] = __builtin_amdgcn_mfma_f32_16x16x32_f16(a1h, bh, acc[1][n], 0, 0, 0);
                acc[1][n] = __builtin_amdgcn_mfma_f32_16x16x32_f16(a1l, bh, acc[1][n], 0, 0, 0);
                acc[1][n] = __builtin_amdgcn_mfma_f32_16x16x32_f16(a1h, bl, acc[1][n], 0, 0, 0);
            }
        }
        // top-2 update; per (lane,row) col sequence strictly increasing
        #pragma unroll
        for (int t = 0; t < 2; ++t) {
            #pragma unroll
            for (int n = 0; n < 4; ++n) {
                int col = dbase0 + nq * 64 + n * 16 + laneN;
                #pragma unroll
                for (int q = 0; q < 4; ++q) {
                    float v = acc[t][n][q];
                    int st = t * 4 + q;
                    if (v > B1[st]) { B2[st] = B1[st]; I2[st] = I1[st]; B1[st] = v; I1[st] = col; }
                    else if (v > B2[st]) { B2[st] = v; I2[st] = col; }
                }
            }
        }
    }
    __syncthreads();  // done reading A; reuse smem for reduction

    float* rv1 = (float*)smem;            // [32][64]
    int*   ri1 = (int*)(smem + 8192);
    float* rv2 = (float*)(smem + 16384);
    int*   ri2 = (int*)(smem + 24576);
    #pragma unroll
    for (int st = 0; st < 8; ++st) {
        int t = st >> 2, q = st & 3;
        int row = t * 16 + laneK * 4 + q;
        int slot = w * 16 + laneN;
        rv1[row * 64 + slot] = B1[st]; ri1[row * 64 + slot] = I1[st];
        rv2[row * 64 + slot] = B2[st]; ri2[row * 64 + slot] = I2[st];
    }
    __syncthreads();
    if (tid < 32) {
        float b1 = -3.0e38f, b2 = -3.0e38f;
        int i1 = 0x7fffffff, i2 = 0x7fffffff;
        for (int s = 0; s < 64; ++s) {
            float v = rv1[tid * 64 + s]; int i = ri1[tid * 64 + s];
            if (v > b1 || (v == b1 && i < i1)) { b2 = b1; i2 = i1; b1 = v; i1 = i; }
            else if (v > b2 || (v == b2 && i < i2)) { b2 = v; i2 = i; }
            v = rv2[tid * 64 + s]; i = ri2[tid * 64 + s];
            if (v > b1 || (v == b1 && i < i1)) { b2 = b1; i2 = i1; b1 = v; i1 = i; }
            else if (v > b2 || (v == b2 && i < i2)) { b2 = v; i2 = i; }
        }
        t2v[row0 + tid] = make_float2(b1, b2);
        t2i[row0 + tid] = make_int2(i1, i2);
    }
}

// ---------------------------------------------------------------------------
// Kernel 6: finalize — rescue near-ties with exact fp32 rescoring, write outputs.
// ---------------------------------------------------------------------------
__global__ void finalize_kernel(const float* __restrict__ vecs, const float* __restrict__ mean,
                                const float* __restrict__ stdv, const float* __restrict__ dirs,
                                const int* __restrict__ counts, const int* __restrict__ mi,
                                const unsigned* __restrict__ cum,
                                const float2* __restrict__ t2v, const int2* __restrict__ t2i,
                                float* __restrict__ out, int nrows) {
    int r = blockIdx.x * blockDim.x + threadIdx.x;
    if (r >= nrows) return;
    float2 bv = t2v[r];
    int2 bi = t2i[r];
    int di = bi.x;
    if (bv.x - bv.y <= TAU) {
        float s1 = 0.f, s2 = 0.f;
        for (int k = 0; k < Fd; k += 4) {
            float4 x = *(const float4*)&vecs[(size_t)r * Fd + k];
            float4 m = *(const float4*)&mean[k];
            float4 s = *(const float4*)&stdv[k];
            float4 d1 = *(const float4*)&dirs[(size_t)bi.x * Fd + k];
            float4 d2 = *(const float4*)&dirs[(size_t)bi.y * Fd + k];
            float v0 = (x.x - m.x) / (s.x + EPS);
            float v1 = (x.y - m.y) / (s.y + EPS);
            float v2 = (x.z - m.z) / (s.z + EPS);
            float v3 = (x.w - m.w) / (s.w + EPS);
            s1 += v0 * d1.x + v1 * d1.y + v2 * d1.z + v3 * d1.w;
            s2 += v0 * d2.x + v1 * d2.y + v2 * d2.z + v3 * d2.w;
        }
        if (s2 > s1 || (s2 == s1 && bi.y < bi.x)) di = bi.y;
    }
    int c = counts[mi[r] * Dd + di];
    unsigned tot = cum[NBINS - 1];
    if (tot == 0u) tot = 1u;
    float tf = (float)tot;
    int cc = min(max(c, 0), NBINS - 1);
    float cl = (float)cum[cc];
    out[r] = (float)c;
    out[nrows + r] = (float)c / tf;
    out[2 * nrows + r] = (cl - 0.5f * (float)c) / tf;
}

// ---------------------------------------------------------------------------
// Legacy fallback (round-1 fp32 path) used only if ws_size is too small.
// ---------------------------------------------------------------------------
#define BM 32
#define BN 128
#define KC 64
#define AS_LD 260
#define BS_LD 68

__global__ __launch_bounds__(256, 2) void gemm_argmax_kernel(
        const float* __restrict__ vecs, const float* __restrict__ mean,
        const float* __restrict__ stdv, const float* __restrict__ dirs,
        const int* __restrict__ counts, const int* __restrict__ mi,
        const unsigned* __restrict__ cum, float* __restrict__ out, int nrows) {
    __shared__ float As[BM * AS_LD];
    __shared__ float Bs[BN * BS_LD];
    int tid = threadIdx.x;
    int tx = tid & 15, ty = tid >> 4;
    int row0 = blockIdx.x * BM;

    #pragma unroll
    for (int it = 0; it < 8; ++it) {
        int idx = it * 256 + tid;
        int r = idx >> 6, kv = idx & 63;
        float4 x = *(const float4*)&vecs[(row0 + r) * Fd + kv * 4];
        float4 m = *(const float4*)&mean[kv * 4];
        float4 s = *(const float4*)&stdv[kv * 4];
        float4 v;
        v.x = (x.x - m.x) / (s.x + EPS);
        v.y = (x.y - m.y) / (s.y + EPS);
        v.z = (x.z - m.z) / (s.z + EPS);
        v.w = (x.w - m.w) / (s.w + EPS);
        *(float4*)&As[r * AS_LD + kv * 4] = v;
    }

    float best0 = -INFINITY, best1 = -INFINITY;
    int bidx0 = 0, bidx1 = 0;

    for (int ct = 0; ct < Dd / BN; ++ct) {
        float acc[2][8];
        #pragma unroll
        for (int j = 0; j < 8; ++j) { acc[0][j] = 0.f; acc[1][j] = 0.f; }

        for (int kc = 0; kc < Fd / KC; ++kc) {
            __syncthreads();
            #pragma unroll
            for (int it = 0; it < 8; ++it) {
                int idx = it * 256 + tid;
                int r = idx >> 4, kv = idx & 15;
                float4 b = *(const float4*)&dirs[(ct * BN + r) * Fd + kc * KC + kv * 4];
                *(float4*)&Bs[r * BS_LD + kv * 4] = b;
            }
            __syncthreads();
            int kbase = kc * KC;
            #pragma unroll
            for (int ks = 0; ks < KC; ks += 4) {
                float4 a0 = *(const float4*)&As[ty * AS_LD + kbase + ks];
                float4 a1 = *(const float4*)&As[(ty + 16) * AS_LD + kbase + ks];
                #pragma unroll
                for (int j = 0; j < 8; ++j) {
                    float4 b = *(const float4*)&Bs[(tx + 16 * j) * BS_LD + ks];
                    acc[0][j] += a0.x * b.x + a0.y * b.y + a0.z * b.z + a0.w * b.w;
                    acc[1][j] += a1.x * b.x + a1.y * b.y + a1.z * b.z + a1.w * b.w;
                }
            }
        }
        #pragma unroll
        for (int j = 0; j < 8; ++j) {
            int gc = ct * BN + tx + 16 * j;
            if (acc[0][j] > best0) { best0 = acc[0][j]; bidx0 = gc; }
            if (acc[1][j] > best1) { best1 = acc[1][j]; bidx1 = gc; }
        }
    }

    __syncthreads();
    float* redv = As;
    int* redi = (int*)&As[BM * 16];
    redv[ty * 16 + tx] = best0;        redi[ty * 16 + tx] = bidx0;
    redv[(ty + 16) * 16 + tx] = best1; redi[(ty + 16) * 16 + tx] = bidx1;
    __syncthreads();
    if (tid < BM) {
        float bv = redv[tid * 16];
        int bi = redi[tid * 16];
        #pragma unroll
        for (int t = 1; t < 16; ++t) {
            float v = redv[tid * 16 + t];
            int ii = redi[tid * 16 + t];
            if (v > bv || (v == bv && ii < bi)) { bv = v; bi = ii; }
        }
        int gr = row0 + tid;
        if (gr < nrows) {
            int mival = mi[gr];
            int c = counts[mival * Dd + bi];
            unsigned totU = cum[NBINS - 1];
            if (totU == 0u) totU = 1u;
            float tf = (float)totU;
            int cc = min(max(c, 0), NBINS - 1);
            float cl = (float)cum[cc];
            out[gr] = (float)c;
            out[nrows + gr] = (float)c / tf;
            out[2 * nrows + gr] = (cl - 0.5f * (float)c) / tf;
        }
    }
}

// ---------------------------------------------------------------------------
extern "C" void kernel_launch(void* const* d_in, const int* in_sizes, int n_in,
                              void* d_out, int out_size, void* d_ws, size_t ws_size,
                              hipStream_t stream) {
    const float* vecs = (const float*)d_in[0];
    const float* mean = (const float*)d_in[1];
    const float* stdv = (const float*)d_in[2];
    const float* mags = (const float*)d_in[3];
    const float* dirs = (const float*)d_in[4];
    const int* counts = (const int*)d_in[5];
    float* out = (float*)d_out;

    char* ws = (char*)d_ws;
    unsigned* W = (unsigned*)(ws + WS_W);
    unsigned* cum = (unsigned*)(ws + WS_CUM);
    int* mi = (int*)(ws + WS_MI);

    int nC = in_sizes[5];  // M*D = 262144

    hipMemsetAsync(W, 0, NBINS * sizeof(unsigned), stream);
    hist_kernel<<<256, 256, 0, stream>>>(counts, W, nC);
    scan_kernel<<<1, NBINS, 0, stream>>>(W, cum);
    norm_mi_kernel<<<Bn / 4, 256, 0, stream>>>(
        (const float4*)vecs, (const float4*)mean, (const float4*)stdv, mags, mi, Bn);

    if (ws_size >= WS_NEEDED) {
        float2* t2v = (float2*)(ws + WS_T2V);
        int2* t2i = (int2*)(ws + WS_T2I);
        _Float16* dh = (_Float16*)(ws + WS_DH);
        _Float16* dl = (_Float16*)(ws + WS_DL);

        split_dirs_kernel<<<(Dd * Fd / 4) / 256, 256, 0, stream>>>(
            (const float4*)dirs, (half4v*)dh, (half4v*)dl, Dd * Fd / 4);
        mfma_top2_kernel<<<Bn / 32, 256, 0, stream>>>(vecs, mean, stdv, dh, dl, t2v, t2i);
        finalize_kernel<<<Bn / 256, 256, 0, stream>>>(
            vecs, mean, stdv, dirs, counts, mi, cum, t2v, t2i, out, Bn);
    } else {
        gemm_argmax_kernel<<<Bn / BM, 256, 0, stream>>>(
            vecs, mean, stdv, dirs, counts, mi, cum, out, Bn);
    }
}